// Round 7
// baseline (34.504 us; speedup 1.0000x reference)
//
#include <hip/hip_runtime.h>

// out[n,k] = sum_{i,j} x[n,i] * W[k,i,j] * x[n,j]   (N=262144 rows, D=32)
// GEMM form: z[n, p=i*32+j] = x[n,i]*x[n,j];  out = z (N x 1024) @ Wf (1024 x 32),
// Wf[p][k] = W[k*1024 + p].  v_mfma_f32_32x32x16_f16, fp32 accumulate.
//
// R7 vs R6 (33.2us): THEORY = instruction-cache thrash. The fully-unrolled
// 64-step K-loop is ~15K instr (~120KB) vs 32KB L1I; all three prior
// structures (31.5-33.2us) shared it, and both pipes were throttled by the
// same factor (R2: VALUBusy 27%, MfmaUtil 11% ~ static ratio / 3.5).
// Fix: ROLLED loop, 8 iterations x 2 groups (~1KB body).
//  - x rows staged in LDS (coalesced float4 loads -> packed f16 pairs,
//    stride 20 u32); in-loop xi = 1 ds_read_b32 per tile per group
//    (runtime-indexed registers would spill - rule: static indexing only).
//  - bt (f16 B-fragment table, prep kernel, 64KiB in d_ws) read from L2,
//    register double-buffered two groups ahead (bfA/bfB ping-pong).
//    Last iteration over-reads 4KiB past the table into d_ws - harmless.
//  - launch_bounds(256,4): ~90 live regs, cap 128, 16 waves/CU.

typedef _Float16 f16x2 __attribute__((ext_vector_type(2)));
typedef _Float16 f16x8 __attribute__((ext_vector_type(8)));
typedef float    f32x16 __attribute__((ext_vector_type(16)));

static __device__ __forceinline__ unsigned int pk2_f16(float lo, float hi) {
    return __builtin_bit_cast(unsigned int, __builtin_amdgcn_cvt_pkrtz(lo, hi));
}

// ---- prep: build f16 fragment table in ws ----
// bt[s*64 + l] (16B) = f16 of Wf[16s + (l>>5)*8 + b][l&31], b=0..7
//                    = f16 of W[(l&31)*1024 + s*16 + (l>>5)*8 + b]
__global__ __launch_bounds__(512)
void prep_btab(const float* __restrict__ W, uint4* __restrict__ bt) {
    int idx = blockIdx.x * 512 + threadIdx.x;     // 0..4095
    int s = idx >> 6;
    int l = idx & 63;
    const float* src = W + (l & 31) * 1024 + s * 16 + ((l >> 5) << 3);
    float4 w0 = *(const float4*)(src);
    float4 w1 = *(const float4*)(src + 4);
    uint4 pk;
    pk.x = pk2_f16(w0.x, w0.y);
    pk.y = pk2_f16(w0.z, w0.w);
    pk.z = pk2_f16(w1.x, w1.y);
    pk.w = pk2_f16(w1.z, w1.w);
    bt[idx] = pk;
}

#define XSTRIDE 20   // u32 per row in LDS (16 used + 4 pad: 16B-align + bank spread)

__global__ __launch_bounds__(256, 4)
void quadform_kernel(const float* __restrict__ x,
                     const uint4* __restrict__ bt,
                     float* __restrict__ out) {
    __shared__ unsigned int xlds[256 * XSTRIDE];   // 20 KiB

    const int tid  = threadIdx.x;
    const int lane = tid & 63;
    const int wave = tid >> 6;
    const int hi   = lane >> 5;
    const int rl   = lane & 31;
    const long rowbase = (long)blockIdx.x * 256 + wave * 64;

    // ---- coalesced x load + pack + LDS stage ----
    // float4 idx = it*256+tid: row = idx>>3, pair col cp = (idx&7)*2
    {
        const float4* xsrc = (const float4*)(x + (long)blockIdx.x * 8192);
        #pragma unroll
        for (int it = 0; it < 8; ++it) {
            int idx = it * 256 + tid;
            float4 v = xsrc[idx];
            int row = idx >> 3;
            int cp  = (idx & 7) * 2;
            uint2 w2;
            w2.x = pk2_f16(v.x, v.y);
            w2.y = pk2_f16(v.z, v.w);
            *(uint2*)(&xlds[row * XSTRIDE + cp]) = w2;   // 8B-aligned (stride even)
        }
    }
    __syncthreads();

    // xsel[r][q*4+t]: pair-reg for A-slots (b=2t,2t+1), parity q:
    //   j = q*16 + hi*8 + 2t -> pair index c = q*8 + hi*4 + t
    const int row0 = wave * 64 + rl;               // local row, tile 0 (tile1 = +32)
    unsigned int xsel[2][8];
    #pragma unroll
    for (int r = 0; r < 2; ++r)
        #pragma unroll
        for (int q = 0; q < 2; ++q) {
            uint4 s4 = *(const uint4*)(&xlds[(row0 + r * 32) * XSTRIDE + q * 8 + hi * 4]);
            xsel[r][q * 4 + 0] = s4.x;
            xsel[r][q * 4 + 1] = s4.y;
            xsel[r][q * 4 + 2] = s4.z;
            xsel[r][q * 4 + 3] = s4.w;
        }

    f32x16 acc[2];
    #pragma unroll
    for (int r = 0; r < 2; ++r)
        #pragma unroll
        for (int e = 0; e < 16; ++e) acc[r][e] = 0.0f;

    const uint4* pb = bt + lane;                    // + (4g+u)*64 per fragment
    const unsigned int* xrow = &xlds[row0 * XSTRIDE];  // + g ; tile1 at +32*XSTRIDE

    // one K-group g = 4 MFMA steps x 2 tiles, using x-pair g of each row
#define COMPUTE_GROUP(G, BF)                                                    \
    {                                                                           \
        unsigned int xiu[2];                                                    \
        xiu[0] = xrow[(G)];                                                     \
        xiu[1] = xrow[(G) + 32 * XSTRIDE];                                      \
        _Pragma("unroll")                                                       \
        for (int u = 0; u < 4; ++u) {                                           \
            const int q = u & 1;                                                \
            const unsigned int sel = (u >= 2) ? 0x03020302u : 0x01000100u;      \
            _Pragma("unroll")                                                   \
            for (int r = 0; r < 2; ++r) {                                       \
                f16x2 xi2 = __builtin_bit_cast(                                 \
                    f16x2, __builtin_amdgcn_perm(xiu[r], xiu[r], sel));         \
                union { f16x8 v; unsigned int uu[4]; } a;                       \
                _Pragma("unroll")                                               \
                for (int t = 0; t < 4; ++t) {                                   \
                    f16x2 p = xi2 * __builtin_bit_cast(f16x2, xsel[r][q*4+t]);  \
                    a.uu[t] = __builtin_bit_cast(unsigned int, p);              \
                }                                                               \
                acc[r] = __builtin_amdgcn_mfma_f32_32x32x16_f16(                \
                             a.v, __builtin_bit_cast(f16x8, (BF)[u]), acc[r],   \
                             0, 0, 0);                                          \
            }                                                                   \
        }                                                                       \
    }

    // rolled K loop: 8 iterations x 2 groups, bt double-buffered in regs
    uint4 bfA[4], bfB[4];
    #pragma unroll
    for (int u = 0; u < 4; ++u) bfA[u] = pb[u * 64];            // g = 0
    for (int g = 0; g < 16; g += 2) {
        #pragma unroll
        for (int u = 0; u < 4; ++u) bfB[u] = pb[(4 * (g + 1) + u) * 64];
        COMPUTE_GROUP(g, bfA)
        #pragma unroll
        for (int u = 0; u < 4; ++u) bfA[u] = pb[(4 * (g + 2) + u) * 64];
        // (g=14: reads 4KiB past the 64KiB table, still inside d_ws - unused)
        COMPUTE_GROUP(g + 1, bfB)
    }
#undef COMPUTE_GROUP

    // ---- store: col = lane&31 (k), row = (e&3) + 8*(e>>2) + 4*hi ----
    #pragma unroll
    for (int r = 0; r < 2; ++r) {
        long n0 = rowbase + r * 32;
        #pragma unroll
        for (int e = 0; e < 16; ++e) {
            int row = (e & 3) + 8 * (e >> 2) + 4 * hi;
            out[(n0 + row) * 32 + rl] = acc[r][e];
        }
    }
}

extern "C" void kernel_launch(void* const* d_in, const int* in_sizes, int n_in,
                              void* d_out, int out_size, void* d_ws, size_t ws_size,
                              hipStream_t stream) {
    const float* x = (const float*)d_in[0];
    const float* W = (const float*)d_in[1];
    float* out = (float*)d_out;
    uint4* bt = (uint4*)d_ws;                  // 64 KiB fragment table (+4KiB slack)

    prep_btab<<<8, 512, 0, stream>>>(W, bt);
    int nrows = in_sizes[0] / 32;              // 262144
    int grid  = nrows / 256;                   // 1024 blocks of 256 thr
    quadform_kernel<<<grid, 256, 0, stream>>>(x, bt, out);
}

// Round 8
// 32.487 us; speedup vs baseline: 1.0621x; 1.0621x over previous
//
#include <hip/hip_runtime.h>

// out[n,k] = sum_{i,j} x[n,i] * W[k,i,j] * x[n,j]   (N=262144 rows, D=32)
// GEMM form: z[n, p=i*32+j] = x[n,i]*x[n,j];  out = z (N x 1024) @ Wf (1024 x 32),
// Wf[p][k] = W[k*1024 + p].  v_mfma_f32_32x32x16_f16, fp32 accumulate.
//
// R8 theory: all prior structures (31.5-34.5us) used exactly ONE wave
// generation (4096 waves = machine capacity), phase-locked: x-read burst,
// compute, store drain all serialized (~26-31us sum). Falsified so far:
// spill (R6), coalescing (R5), LDS/barriers (R6), bt-LDS-vs-L2 (R4/5 vs 6/7),
// I$ (R7), TLP 2-vs-4 waves/SIMD (R6 vs R7, equal).
// Fix: persistent blocks, 2 chunks of 512 rows each; chunk1's x loads are
// issued BEFORE chunk0's K-loop (latency hidden under MFMA), chunk0's store
// drain overlaps chunk1's work; btab built once per block; no prep kernel.
// K-loop / math / layouts byte-identical to R5 (absmax 0.25 preserved).

typedef _Float16 f16x2 __attribute__((ext_vector_type(2)));
typedef _Float16 f16x8 __attribute__((ext_vector_type(8)));
typedef float    f32x16 __attribute__((ext_vector_type(16)));

static __device__ __forceinline__ unsigned int pk2_f16(float lo, float hi) {
    return __builtin_bit_cast(unsigned int, __builtin_amdgcn_cvt_pkrtz(lo, hi));
}

struct XPack {
    unsigned int xpk[2][16];   // packed f16 pair (x[2c], x[2c+1]) per row-tile
    unsigned int xsel[2][8];   // hi-selected pair regs feeding A-slots
};

static __device__ __forceinline__
void load_xg(float4 xg[16], const float* __restrict__ x, long wrow0, int rl) {
    #pragma unroll
    for (int r = 0; r < 2; ++r) {
        const float4* xr = (const float4*)(x + (wrow0 + r * 32 + rl) * 32);
        #pragma unroll
        for (int c = 0; c < 8; ++c) xg[r * 8 + c] = xr[c];
    }
}

static __device__ __forceinline__
void pack_rows(const float4 xg[16], int hi, XPack& P) {
    #pragma unroll
    for (int r = 0; r < 2; ++r) {
        #pragma unroll
        for (int c = 0; c < 8; ++c) {
            float4 v = xg[r * 8 + c];
            P.xpk[r][2 * c + 0] = pk2_f16(v.x, v.y);
            P.xpk[r][2 * c + 1] = pk2_f16(v.z, v.w);
        }
        // xsel[r][q*4+t]: pair for A-slots (b=2t,2t+1), parity q:
        //   j = q*16 + hi*8 + 2t -> pair index c = q*8 + hi*4 + t
        #pragma unroll
        for (int q = 0; q < 2; ++q)
            #pragma unroll
            for (int t = 0; t < 4; ++t)
                P.xsel[r][q * 4 + t] = hi ? P.xpk[r][q * 8 + 4 + t]
                                          : P.xpk[r][q * 8 + t];
    }
}

static __device__ __forceinline__
void kloop_store(const unsigned short* __restrict__ btab, const XPack& P,
                 int lane, int hi, int rl, long wrow0, float* __restrict__ out) {
    f32x16 acc[2];
    #pragma unroll
    for (int r = 0; r < 2; ++r)
        #pragma unroll
        for (int e = 0; e < 16; ++e) acc[r][e] = 0.0f;

    // 64 K-steps of K=16 (p = 16s+k), fully unrolled (R5 structure)
    #pragma unroll
    for (int s = 0; s < 64; ++s) {
        f16x8 bfrag = *(const f16x8*)(&btab[(s * 64 + lane) * 8]);
        const int ii = s >> 1;           // i (fixed within step)
        const int q  = s & 1;
        const unsigned int sel = (ii & 1) ? 0x03020302u : 0x01000100u;
        #pragma unroll
        for (int r = 0; r < 2; ++r) {
            unsigned int w = P.xpk[r][ii >> 1];
            f16x2 xi2 = __builtin_bit_cast(f16x2, __builtin_amdgcn_perm(w, w, sel));
            union { f16x8 v; unsigned int uu[4]; } a;
            #pragma unroll
            for (int t = 0; t < 4; ++t) {
                f16x2 p = xi2 * __builtin_bit_cast(f16x2, P.xsel[r][q * 4 + t]);
                a.uu[t] = __builtin_bit_cast(unsigned int, p);
            }
            acc[r] = __builtin_amdgcn_mfma_f32_32x32x16_f16(a.v, bfrag, acc[r], 0, 0, 0);
        }
    }

    // store: col = lane&31 (k), row = (e&3) + 8*(e>>2) + 4*hi
    #pragma unroll
    for (int r = 0; r < 2; ++r) {
        long n0 = wrow0 + r * 32;
        #pragma unroll
        for (int e = 0; e < 16; ++e) {
            int row = (e & 3) + 8 * (e >> 2) + 4 * hi;
            out[(n0 + row) * 32 + rl] = acc[r][e];
        }
    }
}

__global__ __launch_bounds__(512, 2)
void quadform_kernel(const float* __restrict__ x,
                     const float* __restrict__ W,
                     float* __restrict__ out) {
    // btab[(s*64 + lane)*8 + b] = f16 of Wf[16s + (lane>>5)*8 + b][lane&31]
    __shared__ __align__(16) unsigned short btab[64 * 64 * 8];   // 64 KiB

    const int tid  = threadIdx.x;
    const int lane = tid & 63;
    const int wave = tid >> 6;
    const int hi   = lane >> 5;
    const int rl   = lane & 31;
    const long wrow0 = (long)blockIdx.x * 1024 + wave * 64;   // chunk0 wave base

    // ---- chunk 0 x loads issued first (hide under btab build) ----
    float4 xg[16];
    load_xg(xg, x, wrow0, rl);

    // ---- build LDS B-table from global W (fp32 -> f16 fragments), once ----
    #pragma unroll
    for (int f = 0; f < 8; ++f) {
        int idx = tid + f * 512;                 // 0..4095 fragments (s,l)
        int s = idx >> 6;
        int l = idx & 63;
        const float* src = W + (l & 31) * 1024 + s * 16 + ((l >> 5) << 3);
        float4 w0 = *(const float4*)(src);
        float4 w1 = *(const float4*)(src + 4);
        union { unsigned int ui[4]; uint4 u4; } pk;
        pk.ui[0] = pk2_f16(w0.x, w0.y);
        pk.ui[1] = pk2_f16(w0.z, w0.w);
        pk.ui[2] = pk2_f16(w1.x, w1.y);
        pk.ui[3] = pk2_f16(w1.z, w1.w);
        *(uint4*)(&btab[idx * 8]) = pk.u4;
    }
    __syncthreads();

    XPack P;
    // ---- chunk 0: pack, then PREFETCH chunk 1's x before the K-loop ----
    pack_rows(xg, hi, P);                       // consumes chunk0 loads
    load_xg(xg, x, wrow0 + 512, rl);            // chunk1 loads: in flight during K-loop
    kloop_store(btab, P, lane, hi, rl, wrow0, out);

    // ---- chunk 1 (stores of chunk 0 drain under this work) ----
    pack_rows(xg, hi, P);
    kloop_store(btab, P, lane, hi, rl, wrow0 + 512, out);
}

extern "C" void kernel_launch(void* const* d_in, const int* in_sizes, int n_in,
                              void* d_out, int out_size, void* d_ws, size_t ws_size,
                              hipStream_t stream) {
    const float* x = (const float*)d_in[0];
    const float* W = (const float*)d_in[1];
    float* out = (float*)d_out;
    int nrows = in_sizes[0] / 32;          // 262144
    int grid  = nrows / 1024;              // 256 blocks x 512 thr, 2 chunks each
    quadform_kernel<<<grid, 512, 0, stream>>>(x, W, out);
}